// Round 1
// baseline (200.009 us; speedup 1.0000x reference)
//
#include <hip/hip_runtime.h>
#include <hip/hip_bf16.h>
#include <math.h>

typedef __bf16 bf16;
typedef float f32x4 __attribute__((ext_vector_type(4)));
typedef bf16 bf16x8 __attribute__((ext_vector_type(8)));

#define MTOT 16384
#define HALF 8192
#define KDIM 256
#define BM 128
#define BK 32
#define NB (MTOT / BM)            /* 128 block-rows */
#define NBLK (NB * (NB + 1) / 2)  /* 8256 upper-triangle blocks */

#define GLDS16(g, l) __builtin_amdgcn_global_load_lds(                      \
    (const __attribute__((address_space(1))) void*)(g),                     \
    (__attribute__((address_space(3))) void*)(l), 16, 0, 0)

// ---------------------------------------------------------------------------
// Pass 1: fp32 -> bf16 convert of stacked Z = [N; R], plus per-row squared
// norms computed FROM THE BF16 VALUES (this is what makes the diagonal of the
// kernel matrix come out at exp(~0)=1 despite bf16 MFMA).
// ---------------------------------------------------------------------------
__global__ __launch_bounds__(256) void convert_kernel(
    const float* __restrict__ Nmat, const float* __restrict__ Rmat,
    bf16* __restrict__ Z, float* __restrict__ x2) {
  int row = blockIdx.x;        // 0..16383
  int t = threadIdx.x;         // 0..255 == KDIM
  const float* src = (row < HALF) ? (Nmat + (size_t)row * KDIM)
                                  : (Rmat + (size_t)(row - HALF) * KDIM);
  float v = src[t];
  bf16 b = (bf16)v;            // RNE round to bf16
  Z[(size_t)row * KDIM + t] = b;
  float vb = (float)b;         // exact
  float sq = vb * vb;
  #pragma unroll
  for (int off = 32; off; off >>= 1) sq += __shfl_down(sq, off);
  __shared__ float ws[4];
  if ((t & 63) == 0) ws[t >> 6] = sq;
  __syncthreads();
  if (t == 0) x2[row] = ws[0] + ws[1] + ws[2] + ws[3];
}

// ---------------------------------------------------------------------------
// Pass 2: upper-block-triangular S = Z Z^T with fused RBF + signed reduction.
// Block = 256 threads = 4 waves in 2x2; each wave owns 64x64 = 4x4 MFMA tiles.
// ---------------------------------------------------------------------------
__global__ __launch_bounds__(256) void mmd_gemm(
    const bf16* __restrict__ Z, const float* __restrict__ x2,
    float* __restrict__ accum) {
  // Decode linear block id -> (bm, bn) with bn >= bm (uniform scalar loop).
  int rem = blockIdx.x;
  int bm = 0;
  while (rem >= NB - bm) { rem -= NB - bm; ++bm; }
  int bn = bm + rem;

  __shared__ bf16 As[BM * BK];   // [128][32] row-major, 8 KB
  __shared__ bf16 Bs[BM * BK];
  __shared__ float wsum[4];

  const int tid  = threadIdx.x;
  const int lane = tid & 63;
  const int wid  = tid >> 6;       // 0..3
  const int wm   = wid >> 1;       // wave row (0..1)
  const int wn   = wid & 1;        // wave col (0..1)

  // Staging geometry: each wave-instruction fills 16 LDS rows (1024 B);
  // lane l -> row l/4, 16B chunk l%4 (matches HW dest = base + lane*16).
  const int lrow   = lane >> 2;    // 0..15
  const int lchunk = lane & 3;     // 0..3

  const bf16* Abase = Z + (size_t)bm * BM * KDIM;
  const bf16* Bbase = Z + (size_t)bn * BM * KDIM;

  // Fragment geometry (16x16x32 bf16): A[m=lane&15][k=(lane>>4)*8+j],
  // B[k][n=lane&15], C/D: col=lane&15, row=(lane>>4)*4+reg.
  const int fr = lane & 15;
  const int fq = lane >> 4;

  f32x4 zero = {0.f, 0.f, 0.f, 0.f};
  f32x4 acc[4][4];
  #pragma unroll
  for (int i = 0; i < 4; ++i)
    #pragma unroll
    for (int j = 0; j < 4; ++j) acc[i][j] = zero;

  for (int kk = 0; kk < KDIM; kk += BK) {
    #pragma unroll
    for (int q = 0; q < 2; ++q) {
      int slab = wid * 2 + q;                 // 0..7, wave-uniform
      int r = slab * 16 + lrow;               // tile row 0..127
      const bf16* gA = Abase + (size_t)r * KDIM + kk + lchunk * 8;
      const bf16* gB = Bbase + (size_t)r * KDIM + kk + lchunk * 8;
      GLDS16(gA, As + slab * 512);
      GLDS16(gB, Bs + slab * 512);
    }
    __syncthreads();   // drains vmcnt for global_load_lds, then barrier

    bf16x8 af[4], bfg[4];
    #pragma unroll
    for (int tm = 0; tm < 4; ++tm)
      af[tm] = *(const bf16x8*)(As + (wm * 64 + tm * 16 + fr) * BK + fq * 8);
    #pragma unroll
    for (int tn = 0; tn < 4; ++tn)
      bfg[tn] = *(const bf16x8*)(Bs + (wn * 64 + tn * 16 + fr) * BK + fq * 8);
    #pragma unroll
    for (int tm = 0; tm < 4; ++tm)
      #pragma unroll
      for (int tn = 0; tn < 4; ++tn)
        acc[tm][tn] = __builtin_amdgcn_mfma_f32_16x16x32_bf16(
            af[tm], bfg[tn], acc[tm][tn], 0, 0, 0);
    __syncthreads();   // before next staging overwrites LDS
  }

  // Epilogue: d2 = x2[i]+x2[j]-2s, clamp, exp, signed sum.
  float partial = 0.f;
  #pragma unroll
  for (int tm = 0; tm < 4; ++tm) {
    #pragma unroll
    for (int tn = 0; tn < 4; ++tn) {
      int col_g = bn * BM + wn * 64 + tn * 16 + fr;
      float x2c = x2[col_g];
      #pragma unroll
      for (int v = 0; v < 4; ++v) {
        int row_g = bm * BM + wm * 64 + tm * 16 + fq * 4 + v;
        float s = acc[tm][tn][v];
        float d2 = x2[row_g] + x2c - 2.f * s;
        d2 = fmaxf(d2, 0.f);
        partial += __expf(-d2);
      }
    }
  }

  // Block weight: sign(row-half)*sign(col-half); x2 off-diag blocks (symmetry).
  // Row 8192 boundary == block 64, so sign is block-uniform.
  float wgt = ((bm < NB / 2) == (bn < NB / 2)) ? 1.f : -1.f;
  if (bm != bn) wgt *= 2.f;

  #pragma unroll
  for (int off = 32; off; off >>= 1) partial += __shfl_down(partial, off);
  if ((tid & 63) == 0) wsum[wid] = partial;
  __syncthreads();
  if (tid == 0)
    atomicAdd(accum, (wsum[0] + wsum[1] + wsum[2] + wsum[3]) * wgt);
}

__global__ void finalize_kernel(const float* __restrict__ accum,
                                float* __restrict__ out) {
  if (threadIdx.x == 0 && blockIdx.x == 0) {
    float mmd = accum[0] / ((float)HALF * (float)HALF);
    out[0] = sqrtf(fmaxf(mmd, 0.f));
  }
}

extern "C" void kernel_launch(void* const* d_in, const int* in_sizes, int n_in,
                              void* d_out, int out_size, void* d_ws, size_t ws_size,
                              hipStream_t stream) {
  const float* Nmat = (const float*)d_in[0];
  const float* Rmat = (const float*)d_in[1];
  float* out = (float*)d_out;

  char* ws = (char*)d_ws;
  bf16*  Z     = (bf16*)ws;                          // 16384*256*2 = 8 MiB
  float* x2    = (float*)(ws + (size_t)MTOT * KDIM * 2);        // 64 KiB
  float* accum = (float*)(ws + (size_t)MTOT * KDIM * 2 + MTOT * 4);

  hipMemsetAsync(accum, 0, sizeof(float), stream);
  convert_kernel<<<MTOT, 256, 0, stream>>>(Nmat, Rmat, Z, x2);
  mmd_gemm<<<NBLK, 256, 0, stream>>>(Z, x2, accum);
  finalize_kernel<<<1, 64, 0, stream>>>(accum, out);
}

// Round 2
// 185.715 us; speedup vs baseline: 1.0770x; 1.0770x over previous
//
#include <hip/hip_runtime.h>
#include <hip/hip_bf16.h>
#include <hip/hip_fp8.h>
#include <math.h>

typedef float f32x4 __attribute__((ext_vector_type(4)));

#define MTOT 16384
#define HALF 8192
#define KDIM 256                  /* bytes per row in fp8 Z */
#define BM 128
#define BK 64                     /* fp8 elements (= bytes) per K-slab */
#define NB (MTOT / BM)            /* 128 block-rows */
#define NBLK (NB * (NB + 1) / 2)  /* 8256 upper-triangle blocks */

#define GLDS16(g, l) __builtin_amdgcn_global_load_lds(                      \
    (const __attribute__((address_space(1))) void*)(g),                     \
    (__attribute__((address_space(3))) void*)(l), 16, 0, 0)

// ---------------------------------------------------------------------------
// Pass 1: fp32 -> fp8 e4m3 (OCP) convert of stacked Z = [N; R]; per-row
// squared norms computed FROM THE QUANTIZED values so the diagonal of the
// kernel matrix cancels to d2 ~ 0 (exp = 1) despite fp8 MFMA.
// One wave per row: lane reads float4, writes uchar4.
// ---------------------------------------------------------------------------
__global__ __launch_bounds__(256) void convert_kernel(
    const float* __restrict__ Nmat, const float* __restrict__ Rmat,
    unsigned char* __restrict__ Z, float* __restrict__ x2) {
  const int lane = threadIdx.x & 63;
  const int wv = threadIdx.x >> 6;
  const int row = blockIdx.x * 4 + wv;          // 0..16383
  const float* src = (row < HALF) ? (Nmat + (size_t)row * KDIM)
                                  : (Rmat + (size_t)(row - HALF) * KDIM);
  float4 v = *(const float4*)(src + lane * 4);
  __hip_fp8_e4m3 q0(v.x), q1(v.y), q2(v.z), q3(v.w);
  uchar4 pk;
  pk.x = q0.__x; pk.y = q1.__x; pk.z = q2.__x; pk.w = q3.__x;
  *(uchar4*)(Z + (size_t)row * KDIM + lane * 4) = pk;
  float d0 = (float)q0, d1 = (float)q1, d2 = (float)q2, d3 = (float)q3;
  float sq = d0 * d0 + d1 * d1 + d2 * d2 + d3 * d3;
  #pragma unroll
  for (int off = 32; off; off >>= 1) sq += __shfl_down(sq, off);
  if (lane == 0) x2[row] = sq;
}

// ---------------------------------------------------------------------------
// Pass 2: upper-block-triangular S = Z Z^T (fp8 MFMA) with fused RBF +
// signed reduction. 256 threads = 4 waves in 2x2; each wave owns 64x64 =
// 4x4 grid of 16x16x32 fp8 MFMA tiles; BK=64 -> 2 k-steps per staged slab.
// LDS chunk-XOR swizzle (chunk ^= row&3, applied on the GLOBAL source so the
// wave-uniform global_load_lds dest rule holds) makes fragment ds_read_b64
// conflict-free.
// ---------------------------------------------------------------------------
__global__ __launch_bounds__(256) void mmd_gemm(
    const unsigned char* __restrict__ Z, const float* __restrict__ x2,
    float* __restrict__ accum) {
  // Decode linear block id -> (bm, bn), bn >= bm (uniform scalar loop).
  int rem = blockIdx.x;
  int bm = 0;
  while (rem >= NB - bm) { rem -= NB - bm; ++bm; }
  int bn = bm + rem;

  __shared__ unsigned char As[BM * BK];   // [128][64] bytes, 8 KB
  __shared__ unsigned char Bs[BM * BK];
  __shared__ float wsum[4];

  const int tid  = threadIdx.x;
  const int lane = tid & 63;
  const int wid  = tid >> 6;       // 0..3
  const int wm   = wid >> 1;       // wave row (0..1)
  const int wn   = wid & 1;        // wave col (0..1)

  // Staging: each GLDS16 fills 1024 B = 16 rows x 64 B at base + lane*16.
  const int lrow   = lane >> 2;            // 0..15 within slab
  const int lchunk = (lane & 3) ^ (lrow & 3);  // XOR-swizzled source chunk

  const unsigned char* Abase = Z + (size_t)bm * BM * KDIM;
  const unsigned char* Bbase = Z + (size_t)bn * BM * KDIM;

  // Fragment geometry (16x16x32 fp8, same blocked layout as bf16 k=quad*8+j):
  const int fr = lane & 15;
  const int fq = lane >> 4;        // 0..3
  const int fsw = fr & 3;          // swizzle key for fragment reads
  const int flo = (fq & 1) * 8;    // low-byte offset within 16B chunk
  const int fhi = fq >> 1;         // chunk half-index

  f32x4 zero = {0.f, 0.f, 0.f, 0.f};
  f32x4 acc[4][4];
  #pragma unroll
  for (int i = 0; i < 4; ++i)
    #pragma unroll
    for (int j = 0; j < 4; ++j) acc[i][j] = zero;

  for (int kk = 0; kk < KDIM; kk += BK) {
    #pragma unroll
    for (int q = 0; q < 2; ++q) {
      int slab = wid * 2 + q;                 // 0..7, wave-uniform
      int r = slab * 16 + lrow;               // tile row 0..127
      const unsigned char* gA = Abase + (size_t)r * KDIM + kk + lchunk * 16;
      const unsigned char* gB = Bbase + (size_t)r * KDIM + kk + lchunk * 16;
      GLDS16(gA, As + slab * 1024);
      GLDS16(gB, Bs + slab * 1024);
    }
    __syncthreads();   // drains vmcnt for global_load_lds, then barrier

    #pragma unroll
    for (int ks = 0; ks < 2; ++ks) {
      long long af[4], bfg[4];
      #pragma unroll
      for (int tm = 0; tm < 4; ++tm) {
        int row = wm * 64 + tm * 16 + fr;
        int off = row * BK + (((ks * 2 + fhi) ^ fsw) * 16) + flo;
        af[tm] = *(const long long*)(As + off);
      }
      #pragma unroll
      for (int tn = 0; tn < 4; ++tn) {
        int row = wn * 64 + tn * 16 + fr;
        int off = row * BK + (((ks * 2 + fhi) ^ fsw) * 16) + flo;
        bfg[tn] = *(const long long*)(Bs + off);
      }
      #pragma unroll
      for (int tm = 0; tm < 4; ++tm)
        #pragma unroll
        for (int tn = 0; tn < 4; ++tn)
          acc[tm][tn] = __builtin_amdgcn_mfma_f32_16x16x32_fp8_fp8(
              af[tm], bfg[tn], acc[tm][tn], 0, 0, 0);
    }
    __syncthreads();   // before next staging overwrites LDS
  }

  // Epilogue: d2 = x2[i]+x2[j]-2s, clamp, exp, signed sum.
  float partial = 0.f;
  #pragma unroll
  for (int tm = 0; tm < 4; ++tm) {
    #pragma unroll
    for (int tn = 0; tn < 4; ++tn) {
      int col_g = bn * BM + wn * 64 + tn * 16 + fr;
      float x2c = x2[col_g];
      #pragma unroll
      for (int v = 0; v < 4; ++v) {
        int row_g = bm * BM + wm * 64 + tm * 16 + fq * 4 + v;
        float s = acc[tm][tn][v];
        float d2 = x2[row_g] + x2c - 2.f * s;
        d2 = fmaxf(d2, 0.f);
        partial += __expf(-d2);
      }
    }
  }

  // Block weight: sign(N/R half)*sign; off-diag blocks x2 (symmetry).
  // Row 8192 boundary == block 64, so sign is block-uniform.
  float wgt = ((bm < NB / 2) == (bn < NB / 2)) ? 1.f : -1.f;
  if (bm != bn) wgt *= 2.f;

  #pragma unroll
  for (int off = 32; off; off >>= 1) partial += __shfl_down(partial, off);
  if ((tid & 63) == 0) wsum[wid] = partial;
  __syncthreads();
  if (tid == 0)
    atomicAdd(accum, (wsum[0] + wsum[1] + wsum[2] + wsum[3]) * wgt);
}

__global__ void finalize_kernel(const float* __restrict__ accum,
                                float* __restrict__ out) {
  if (threadIdx.x == 0 && blockIdx.x == 0) {
    float mmd = accum[0] / ((float)HALF * (float)HALF);
    out[0] = sqrtf(fmaxf(mmd, 0.f));
  }
}

extern "C" void kernel_launch(void* const* d_in, const int* in_sizes, int n_in,
                              void* d_out, int out_size, void* d_ws, size_t ws_size,
                              hipStream_t stream) {
  const float* Nmat = (const float*)d_in[0];
  const float* Rmat = (const float*)d_in[1];
  float* out = (float*)d_out;

  char* ws = (char*)d_ws;
  unsigned char* Z = (unsigned char*)ws;                     // 16384*256 = 4 MiB
  float* x2    = (float*)(ws + (size_t)MTOT * KDIM);         // 64 KiB
  float* accum = (float*)(ws + (size_t)MTOT * KDIM + MTOT * 4);

  hipMemsetAsync(accum, 0, sizeof(float), stream);
  convert_kernel<<<MTOT / 4, 256, 0, stream>>>(Nmat, Rmat, Z, x2);
  mmd_gemm<<<NBLK, 256, 0, stream>>>(Z, x2, accum);
  finalize_kernel<<<1, 64, 0, stream>>>(accum, out);
}